// Round 5
// baseline (39.469 us; speedup 1.0000x reference)
//
#include <hip/hip_runtime.h>

typedef __attribute__((ext_vector_type(8))) short bf16x8;
typedef __attribute__((ext_vector_type(4))) float f32x4;

#define TT 256
#define SS 5
#define DD 32
#define BPB 4    // batches (b values) per block
#define ZP 21    // zS row stride: gcd(21,32)=1 -> conflict-light

#define MFMA(A, B, C) __builtin_amdgcn_mfma_f32_16x16x32_bf16((A), (B), (C), 0, 0, 0)

__device__ __forceinline__ float frcp(float v) { return __builtin_amdgcn_rcpf(v); }

// pack two fp32 -> two bf16 (RNE) in one dword (first arg in low half)
__device__ __forceinline__ unsigned f2bf2(float lo, float hi) {
    unsigned a = __float_as_uint(lo), b = __float_as_uint(hi);
    a = (a + 0x7fffu + ((a >> 16) & 1u)) >> 16;
    b = (b + 0x7fffu + ((b >> 16) & 1u)) & 0xffff0000u;
    return a | b;
}
// RNE-rounded bf16 value, kept as fp32
__device__ __forceinline__ float bfhi(float v) {
    unsigned a = __float_as_uint(v);
    a = (a + 0x7fffu + ((a >> 16) & 1u)) & 0xffff0000u;
    return __uint_as_float(a);
}

union F8 { unsigned u[4]; bf16x8 v; };

// split 8 fp32 into hi/lo bf16 fragments (Markidis split)
__device__ __forceinline__ void split8(const float4 f0, const float4 f1, F8& h, F8& lo) {
    const float f[8] = {f0.x, f0.y, f0.z, f0.w, f1.x, f1.y, f1.z, f1.w};
    float hv[8], lv[8];
    #pragma unroll
    for (int j = 0; j < 8; ++j) { hv[j] = bfhi(f[j]); lv[j] = f[j] - hv[j]; }
    #pragma unroll
    for (int j = 0; j < 4; ++j) {
        h.u[j]  = (__float_as_uint(hv[2*j]) >> 16) | (__float_as_uint(hv[2*j+1]) & 0xffff0000u);
        lo.u[j] = f2bf2(lv[2*j], lv[2*j+1]);
    }
}

__global__ void __launch_bounds__(256, 4)
mem_net_kernel(const float* __restrict__ x,
               const float* __restrict__ q,
               const float* __restrict__ keys,
               const float* __restrict__ Wu,
               const float* __restrict__ bu,
               const int*   __restrict__ lens,
               const int*   __restrict__ labels,
               const int*   __restrict__ qlab,
               float*       __restrict__ out)
{
    __shared__ __align__(16) float zS[TT][ZP];       // QK logits (intra-wave rows)
    __shared__ float wTot[2][4][SS];                 // per-wave scan totals, parity dbuf
    __shared__ float rSs[2][8];                      // r_attn, parity dbuf
    __shared__ __align__(16) float red[BPB][4][DD];  // per-(b,wave) output partials

    const int b0  = blockIdx.x * BPB;
    const int tid = threadIdx.x;
    const int l   = tid & 63;
    const int w   = tid >> 6;
    const int t   = tid;
    const int n0  = l & 15;
    const int kb  = (l >> 4) << 3;

    const int4 len4 = *reinterpret_cast<const int4*>(lens + b0);
    const int4 qla4 = *reinterpret_cast<const int4*>(qlab + b0);
    const int slen[BPB] = {len4.x, len4.y, len4.z, len4.w};
    const int qla[BPB]  = {qla4.x, qla4.y, qla4.z, qla4.w};

    // ---- K_all^T B-fragments hi/lo (once per block) ----
    F8 kh0, kl0, kh1, kl1;
    {
        const float* kp = keys + (size_t)n0 * DD + kb;
        const float4 g0 = *reinterpret_cast<const float4*>(kp);
        const float4 g1 = *reinterpret_cast<const float4*>(kp + 4);
        split8(g0, g1, kh0, kl0);
        if (n0 < 4) {
            const float* kp1 = keys + (size_t)(16 + n0) * DD + kb;
            const float4 h0 = *reinterpret_cast<const float4*>(kp1);
            const float4 h1 = *reinterpret_cast<const float4*>(kp1 + 4);
            split8(h0, h1, kh1, kl1);
        } else {
            #pragma unroll
            for (int j = 0; j < 4; ++j) { kh1.u[j] = 0u; kl1.u[j] = 0u; }
        }
    }
    // ---- Wu B-fragments + bias (once per block) ----
    F8 bw0, bw1;
    #pragma unroll
    for (int j = 0; j < 4; ++j) {
        const int k0 = kb + 2 * j;
        bw0.u[j] = f2bf2(Wu[k0 * DD + n0],      Wu[(k0 + 1) * DD + n0]);
        bw1.u[j] = f2bf2(Wu[k0 * DD + n0 + 16], Wu[(k0 + 1) * DD + n0 + 16]);
    }
    const float bub0 = bu[n0], bub1 = bu[n0 + 16];

    float4 f[8];        // prefetched x fragments for the upcoming b
    int    labn = 0;    // prefetched label for row t
    float  qn   = 0.f;  // prefetched q value (wave 0)
    float  aw[SS];      // a[s]*excl[s], carried front->back
    F8     xh[4];       // hi fragments, carried front->back

    auto PREFETCH = [&](int i) {
        const int bb   = b0 + i;
        const int lenb = slen[i];
        #pragma unroll
        for (int rt = 0; rt < 4; ++rt) {
            const int rbase = (w << 6) + (rt << 4);
            if (rbase < lenb) {                      // wave-uniform
                const float* xt = x + ((size_t)bb * TT + rbase + n0) * DD + kb;
                f[2 * rt]     = *reinterpret_cast<const float4*>(xt);
                f[2 * rt + 1] = *reinterpret_cast<const float4*>(xt + 4);
            }
        }
        labn = labels[(size_t)bb * TT + t];
        if (w == 0) qn = q[(size_t)bb * DD + (l & 31)];
    };

    auto FRONT = [&](int i) {
        const int  lenb = slen[i];
        const bool wact = (w << 6) < lenb;
        const int  p    = i & 1;
        // QK^T via split-fp32 MFMA, scatter logits to zS (own-wave rows only)
        if (wact) {
            #pragma unroll
            for (int rt = 0; rt < 4; ++rt) {
                const int rbase = (w << 6) + (rt << 4);
                if (rbase < lenb) {
                    F8 xlo;
                    split8(f[2 * rt], f[2 * rt + 1], xh[rt], xlo);
                    f32x4 z0 = {0.f, 0.f, 0.f, 0.f};
                    f32x4 z1 = {0.f, 0.f, 0.f, 0.f};
                    z0 = MFMA(xlo.v,    kh0.v, z0);
                    z0 = MFMA(xh[rt].v, kl0.v, z0);
                    z0 = MFMA(xh[rt].v, kh0.v, z0);
                    z1 = MFMA(xlo.v,    kh1.v, z1);
                    z1 = MFMA(xh[rt].v, kl1.v, z1);
                    z1 = MFMA(xh[rt].v, kh1.v, z1);
                    const int r0 = rbase + ((l >> 4) << 2);
                    #pragma unroll
                    for (int r = 0; r < 4; ++r) zS[r0 + r][n0] = z0[r];
                    if (n0 < 4) {
                        #pragma unroll
                        for (int r = 0; r < 4; ++r) zS[r0 + r][16 + n0] = z1[r];
                    }
                }
            }
        }
        // zS write->read is intra-wave: a waitcnt suffices, no barrier
        asm volatile("s_waitcnt lgkmcnt(0)" ::: "memory");

        // per-row softmax over the 5 label-selected logits (fp32 exact)
        float a[SS];
        #pragma unroll
        for (int s = 0; s < SS; ++s) a[s] = 0.f;
        if (t < lenb) {
            const int lab = (t < lenb - 1) ? labn : 0;
            float z[SS];
            #pragma unroll
            for (int s = 0; s < SS; ++s) z[s] = zS[t][5 * lab + s];
            float m = z[0];
            #pragma unroll
            for (int s = 1; s < SS; ++s) m = fmaxf(m, z[s]);
            float e[SS], sum = 0.f;
            #pragma unroll
            for (int s = 0; s < SS; ++s) { e[s] = __expf(z[s] - m); sum += e[s]; }
            const float inv = frcp(sum);
            #pragma unroll
            for (int s = 0; s < SS; ++s) a[s] = e[s] * inv;
        }

        // suffix-product scan within wave; publish per-wave totals
        if (wact) {
            #pragma unroll
            for (int s = 0; s < SS; ++s) {
                float pr = 1.f - a[s];
                #pragma unroll
                for (int off = 1; off < 64; off <<= 1) {
                    const float o = __shfl_down(pr, off);
                    pr = (l + off < 64) ? pr * o : pr;
                }
                float e = __shfl_down(pr, 1);
                if (l == 63) e = 1.f;
                aw[s] = a[s] * e;
                if (l == 0) wTot[p][w][s] = pr;
            }
        } else {
            #pragma unroll
            for (int s = 0; s < SS; ++s) aw[s] = 0.f;
            if (l == 0) {
                #pragma unroll
                for (int s = 0; s < SS; ++s) wTot[p][w][s] = 1.f;
            }
        }

        // wave 0: r_attn = softmax_s(q . keys[ql][s])
        if (w == 0) {
            const int d = l & 31;
            const int qlb = qla[i];
            float pv[SS];
            #pragma unroll
            for (int s = 0; s < SS; ++s) pv[s] = qn * keys[(size_t)(qlb * SS + s) * DD + d];
            #pragma unroll
            for (int m = 16; m >= 1; m >>= 1) {
                #pragma unroll
                for (int s = 0; s < SS; ++s) pv[s] += __shfl_xor(pv[s], m);
            }
            float mm = pv[0];
            #pragma unroll
            for (int s = 1; s < SS; ++s) mm = fmaxf(mm, pv[s]);
            float e[SS], sum = 0.f;
            #pragma unroll
            for (int s = 0; s < SS; ++s) { e[s] = __expf(pv[s] - mm); sum += e[s]; }
            const float inv = frcp(sum);
            if (l == 0) {
                #pragma unroll
                for (int s = 0; s < SS; ++s) rSs[p][s] = e[s] * inv;
            }
        }
    };

    auto BACK = [&](int i) {
        const int  lenb = slen[i];
        const bool wact = (w << 6) < lenb;
        const int  p    = i & 1;

        // per-row scalar weight c_t (uses cross-wave totals published pre-barrier)
        float c = 0.f;
        if (t < lenb) {
            #pragma unroll
            for (int s = 0; s < SS; ++s) {
                float wsuf = 1.f;
                if (w <= 2) wsuf *= wTot[p][3][s];
                if (w <= 1) wsuf *= wTot[p][2][s];
                if (w == 0) wsuf *= wTot[p][1][s];
                c += rSs[p][s] * (aw[s] * wsuf);
            }
        }

        // MLP MFMA + sigmoid + c_t-weighted reduce
        float p0 = 0.f, p1 = 0.f;
        if (wact) {
            #pragma unroll
            for (int rt = 0; rt < 4; ++rt) {
                const int rbase = (w << 6) + (rt << 4);
                if (rbase < lenb) {
                    f32x4 acc0 = {0.f, 0.f, 0.f, 0.f};
                    f32x4 acc1 = {0.f, 0.f, 0.f, 0.f};
                    acc0 = MFMA(xh[rt].v, bw0.v, acc0);
                    acc1 = MFMA(xh[rt].v, bw1.v, acc1);
                    const int src0 = (rt << 4) + ((l >> 4) << 2);
                    #pragma unroll
                    for (int r = 0; r < 4; ++r) {
                        const float cf = __shfl(c, src0 + r);
                        p0 += cf * frcp(1.f + __expf(-(acc0[r] + bub0)));
                        p1 += cf * frcp(1.f + __expf(-(acc1[r] + bub1)));
                    }
                }
            }
        }
        p0 += __shfl_xor(p0, 16); p0 += __shfl_xor(p0, 32);
        p1 += __shfl_xor(p1, 16); p1 += __shfl_xor(p1, 32);
        if (l < 16) { red[i][w][l] = p0; red[i][w][l + 16] = p1; }
    };

    // ---- pipelined main loop: 1 barrier per b ----
    PREFETCH(0);
    FRONT(0);
    #pragma unroll
    for (int i = 0; i < BPB; ++i) {
        __syncthreads();                       // publishes wTot/rSs parity (i&1)
        if (i + 1 < BPB) PREFETCH(i + 1);      // global loads hide under BACK
        BACK(i);
        if (i + 1 < BPB) FRONT(i + 1);
    }
    __syncthreads();

    if (tid < BPB * DD) {
        const int i = tid >> 5, d = tid & 31;
        out[(size_t)(b0 + i) * DD + d] =
            red[i][0][d] + red[i][1][d] + red[i][2][d] + red[i][3][d];
    }
}

extern "C" void kernel_launch(void* const* d_in, const int* in_sizes, int n_in,
                              void* d_out, int out_size, void* d_ws, size_t ws_size,
                              hipStream_t stream) {
    const float* x      = (const float*)d_in[0];
    const float* q      = (const float*)d_in[1];
    const float* keys   = (const float*)d_in[2];
    const float* Wu     = (const float*)d_in[3];
    const float* bu     = (const float*)d_in[4];
    const int*   lens   = (const int*)d_in[5];
    const int*   labels = (const int*)d_in[6];
    const int*   qlab   = (const int*)d_in[7];
    float* out = (float*)d_out;

    hipLaunchKernelGGL(mem_net_kernel, dim3(4096 / BPB), dim3(256), 0, stream,
                       x, q, keys, Wu, bu, lens, labels, qlab, out);
}

// Round 6
// 32.170 us; speedup vs baseline: 1.2269x; 1.2269x over previous
//
#include <hip/hip_runtime.h>

typedef __attribute__((ext_vector_type(8))) short bf16x8;
typedef __attribute__((ext_vector_type(4))) float f32x4;

#define TT 256
#define SS 5
#define DD 32
#define ZP 260   // zST col stride in words; multiple of 4 (16B-aligned b128 rows)

#define MFMA(A, B, C) __builtin_amdgcn_mfma_f32_16x16x32_bf16((A), (B), (C), 0, 0, 0)

__device__ __forceinline__ float frcp(float v) { return __builtin_amdgcn_rcpf(v); }

// RNE fp32->bf16 rounding of the raw bits (result in high 16)
__device__ __forceinline__ unsigned rneu(unsigned a) { return a + 0x7fffu + ((a >> 16) & 1u); }

// pack two fp32 -> two RNE bf16 in one dword (first arg low half)
__device__ __forceinline__ unsigned f2bf2(float lo, float hi) {
    return (rneu(__float_as_uint(lo)) >> 16) | (rneu(__float_as_uint(hi)) & 0xffff0000u);
}

union F8 { unsigned u[4]; bf16x8 v; };

// split 8 fp32 into hi (RNE bf16) + lo (truncated bf16 of residual) fragments.
// x ~= hi + lo with |err| ~ 2^-17 |x|  (Markidis-style split)
__device__ __forceinline__ void split8(const float4 f0, const float4 f1, F8& h, F8& lo) {
    const float f[8] = {f0.x, f0.y, f0.z, f0.w, f1.x, f1.y, f1.z, f1.w};
    #pragma unroll
    for (int j = 0; j < 4; ++j) {
        const unsigned h0 = rneu(__float_as_uint(f[2*j]))     & 0xffff0000u;
        const unsigned h1 = rneu(__float_as_uint(f[2*j + 1])) & 0xffff0000u;
        h.u[j] = (h0 >> 16) | h1;
        const float l0 = f[2*j]     - __uint_as_float(h0);
        const float l1 = f[2*j + 1] - __uint_as_float(h1);
        lo.u[j] = (__float_as_uint(l0) >> 16) | (__float_as_uint(l1) & 0xffff0000u);
    }
}

__global__ void __launch_bounds__(256, 6)
mem_net_kernel(const float* __restrict__ x,
               const float* __restrict__ q,
               const float* __restrict__ keys,
               const float* __restrict__ Wu,
               const float* __restrict__ bu,
               const int*   __restrict__ lens,
               const int*   __restrict__ labels,
               const int*   __restrict__ qlab,
               float*       __restrict__ out)
{
    __shared__ __align__(16) float zST[20][ZP];   // logits transposed: [col][row]
    __shared__ float wTot[4][SS];
    __shared__ float rS[8];
    __shared__ __align__(16) float cS[TT];
    __shared__ __align__(16) float red[4][DD];

    const int b   = blockIdx.x;
    const int tid = threadIdx.x;
    const int l   = tid & 63;
    const int w   = tid >> 6;
    const int t   = tid;
    const int n0  = l & 15;
    const int g   = l >> 4;
    const int kb  = g << 3;
    const int len = lens[b];
    const int ql  = qlab[b];
    const bool valid = (t < len);
    const bool wact  = ((w << 6) < len);

    // ---- early independent loads ----
    const int labn = labels[(size_t)b * TT + t];
    float qv = 0.f;
    float rkv[SS];
    if (w == 3) {                       // wave 3 owns r_attn (idle in FRONT 75% of time)
        const int d = l & 31;
        qv = q[(size_t)b * DD + d];
        #pragma unroll
        for (int s = 0; s < SS; ++s) rkv[s] = keys[(size_t)(ql * SS + s) * DD + d];
    }

    // ---- K_all^T B-fragments hi/lo ----
    F8 kh0, kl0, kh1, kl1;
    {
        const float* kp = keys + (size_t)n0 * DD + kb;
        const float4 g0 = *reinterpret_cast<const float4*>(kp);
        const float4 g1 = *reinterpret_cast<const float4*>(kp + 4);
        split8(g0, g1, kh0, kl0);
        if (n0 < 4) {
            const float* kp1 = keys + (size_t)(16 + n0) * DD + kb;
            const float4 h0 = *reinterpret_cast<const float4*>(kp1);
            const float4 h1 = *reinterpret_cast<const float4*>(kp1 + 4);
            split8(h0, h1, kh1, kl1);
        } else {
            #pragma unroll
            for (int j = 0; j < 4; ++j) { kh1.u[j] = 0u; kl1.u[j] = 0u; }
        }
    }
    // ---- Wu B-fragments + bias ----
    F8 bw0, bw1;
    #pragma unroll
    for (int j = 0; j < 4; ++j) {
        const int k0 = kb + 2 * j;
        bw0.u[j] = f2bf2(Wu[k0 * DD + n0],      Wu[(k0 + 1) * DD + n0]);
        bw1.u[j] = f2bf2(Wu[k0 * DD + n0 + 16], Wu[(k0 + 1) * DD + n0 + 16]);
    }
    const float bub0 = bu[n0], bub1 = bu[n0 + 16];

    // ---- wave 3: r_attn = softmax_s(q . keys[ql][s])  (pre-barrier publish) ----
    if (w == 3) {
        float pv[SS];
        #pragma unroll
        for (int s = 0; s < SS; ++s) pv[s] = qv * rkv[s];
        #pragma unroll
        for (int m = 16; m >= 1; m >>= 1) {
            #pragma unroll
            for (int s = 0; s < SS; ++s) pv[s] += __shfl_xor(pv[s], m);
        }
        float mm = pv[0];
        #pragma unroll
        for (int s = 1; s < SS; ++s) mm = fmaxf(mm, pv[s]);
        float e[SS], sum = 0.f;
        #pragma unroll
        for (int s = 0; s < SS; ++s) { e[s] = __expf(pv[s] - mm); sum += e[s]; }
        const float inv = frcp(sum);
        if (l == 0) {
            #pragma unroll
            for (int s = 0; s < SS; ++s) rS[s] = e[s] * inv;
        }
    }

    // ---- FRONT: QK^T via split-fp32 MFMA, transposed logit store ----
    F8 xh[4];
    if (wact) {
        #pragma unroll
        for (int rt = 0; rt < 4; ++rt) {
            const int rbase = (w << 6) + (rt << 4);
            if (rbase < len) {                       // wave-uniform
                const float* xt = x + ((size_t)b * TT + rbase + n0) * DD + kb;
                const float4 f0 = *reinterpret_cast<const float4*>(xt);
                const float4 f1 = *reinterpret_cast<const float4*>(xt + 4);
                F8 xlo;
                split8(f0, f1, xh[rt], xlo);
                f32x4 z0 = {0.f, 0.f, 0.f, 0.f};
                f32x4 z1 = {0.f, 0.f, 0.f, 0.f};
                z0 = MFMA(xlo.v,    kh0.v, z0);
                z0 = MFMA(xh[rt].v, kl0.v, z0);
                z0 = MFMA(xh[rt].v, kh0.v, z0);
                z1 = MFMA(xlo.v,    kh1.v, z1);
                z1 = MFMA(xh[rt].v, kl1.v, z1);
                z1 = MFMA(xh[rt].v, kh1.v, z1);
                const int r0 = rbase + (g << 2);     // C layout: col=n0, rows g*4+r
                *reinterpret_cast<f32x4*>(&zST[n0][r0]) = z0;          // b128
                if (n0 < 4)
                    *reinterpret_cast<f32x4*>(&zST[16 + n0][r0]) = z1; // b128
            }
        }
    }
    // zST write->read is same-wave: DS pipe is program-ordered, no barrier needed.

    // ---- softmax over the 5 label-selected logits (fp32 exact) ----
    float a[SS];
    #pragma unroll
    for (int s = 0; s < SS; ++s) a[s] = 0.f;
    if (valid) {
        const int lab = (t < len - 1) ? labn : 0;
        float z[SS];
        #pragma unroll
        for (int s = 0; s < SS; ++s) z[s] = zST[5 * lab + s][t];
        float m = z[0];
        #pragma unroll
        for (int s = 1; s < SS; ++s) m = fmaxf(m, z[s]);
        float e[SS], sum = 0.f;
        #pragma unroll
        for (int s = 0; s < SS; ++s) { e[s] = __expf(z[s] - m); sum += e[s]; }
        const float inv = frcp(sum);
        #pragma unroll
        for (int s = 0; s < SS; ++s) a[s] = e[s] * inv;
    }

    // ---- suffix-product scan within wave; publish per-wave totals ----
    float aw[SS];
    if (wact) {
        #pragma unroll
        for (int s = 0; s < SS; ++s) {
            float pr = 1.f - a[s];
            #pragma unroll
            for (int off = 1; off < 64; off <<= 1) {
                const float o = __shfl_down(pr, off);
                pr = (l + off < 64) ? pr * o : pr;
            }
            float e = __shfl_down(pr, 1);
            if (l == 63) e = 1.f;
            aw[s] = a[s] * e;
            if (l == 0) wTot[w][s] = pr;
        }
    } else {
        #pragma unroll
        for (int s = 0; s < SS; ++s) aw[s] = 0.f;
        if (l == 0) {
            #pragma unroll
            for (int s = 0; s < SS; ++s) wTot[w][s] = 1.f;
        }
    }
    __syncthreads();                       // publishes wTot + rS

    // ---- per-row scalar weight c_t -> cS (intra-wave consumer) ----
    float c = 0.f;
    if (valid) {
        #pragma unroll
        for (int s = 0; s < SS; ++s) {
            float wsuf = 1.f;
            if (w <= 2) wsuf *= wTot[3][s];
            if (w <= 1) wsuf *= wTot[2][s];
            if (w == 0) wsuf *= wTot[1][s];
            c += rS[s] * (aw[s] * wsuf);
        }
    }
    cS[t] = c;
    // cS write->read is same-wave rows: DS pipe ordering suffices.

    // ---- BACK: MLP MFMA + sigmoid + c_t-weighted reduce ----
    float p0 = 0.f, p1 = 0.f;
    if (wact) {
        #pragma unroll
        for (int rt = 0; rt < 4; ++rt) {
            const int rbase = (w << 6) + (rt << 4);
            if (rbase < len) {
                f32x4 acc0 = {0.f, 0.f, 0.f, 0.f};
                f32x4 acc1 = {0.f, 0.f, 0.f, 0.f};
                acc0 = MFMA(xh[rt].v, bw0.v, acc0);
                acc1 = MFMA(xh[rt].v, bw1.v, acc1);
                const float4 cf = *reinterpret_cast<const float4*>(&cS[rbase + (g << 2)]);
                const float cfa[4] = {cf.x, cf.y, cf.z, cf.w};
                #pragma unroll
                for (int r = 0; r < 4; ++r) {
                    p0 += cfa[r] * frcp(1.f + __expf(-(acc0[r] + bub0)));
                    p1 += cfa[r] * frcp(1.f + __expf(-(acc1[r] + bub1)));
                }
            }
        }
    }
    p0 += __shfl_xor(p0, 16); p0 += __shfl_xor(p0, 32);
    p1 += __shfl_xor(p1, 16); p1 += __shfl_xor(p1, 32);
    if (l < 16) { red[w][l] = p0; red[w][l + 16] = p1; }
    __syncthreads();

    if (tid < DD) {
        out[(size_t)b * DD + tid] = red[0][tid] + red[1][tid] + red[2][tid] + red[3][tid];
    }
}

extern "C" void kernel_launch(void* const* d_in, const int* in_sizes, int n_in,
                              void* d_out, int out_size, void* d_ws, size_t ws_size,
                              hipStream_t stream) {
    const float* x      = (const float*)d_in[0];
    const float* q      = (const float*)d_in[1];
    const float* keys   = (const float*)d_in[2];
    const float* Wu     = (const float*)d_in[3];
    const float* bu     = (const float*)d_in[4];
    const int*   lens   = (const int*)d_in[5];
    const int*   labels = (const int*)d_in[6];
    const int*   qlab   = (const int*)d_in[7];
    float* out = (float*)d_out;

    hipLaunchKernelGGL(mem_net_kernel, dim3(4096), dim3(256), 0, stream,
                       x, q, keys, Wu, bu, lens, labels, qlab, out);
}

// Round 7
// 29.311 us; speedup vs baseline: 1.3466x; 1.0975x over previous
//
#include <hip/hip_runtime.h>

typedef __attribute__((ext_vector_type(8))) short bf16x8;
typedef __attribute__((ext_vector_type(4))) float f32x4;

#define TT 256
#define SS 5
#define DD 32
#define ZP 260   // zST col stride (words): mult of 4 (b128 align), %32==4 (conflict-light)

#define MFMA(A, B, C) __builtin_amdgcn_mfma_f32_16x16x32_bf16((A), (B), (C), 0, 0, 0)

__device__ __forceinline__ float frcp(float v) { return __builtin_amdgcn_rcpf(v); }

// packed fp32x2 -> bf16x2 (RNE), single HW instruction
__device__ __forceinline__ unsigned cvtpk(float lo, float hi) {
    unsigned r;
    asm("v_cvt_pk_bf16_f32 %0, %1, %2" : "=v"(r) : "v"(lo), "v"(hi));
    return r;
}

union F8 { unsigned u[4]; bf16x8 v; };

// split 8 fp32 into hi (RNE bf16) + lo (bf16 of residual): x ~= hi+lo, err ~2^-17|x|
__device__ __forceinline__ void split8(const float4 f0, const float4 f1, F8& h, F8& lo) {
    const float f[8] = {f0.x, f0.y, f0.z, f0.w, f1.x, f1.y, f1.z, f1.w};
    #pragma unroll
    for (int j = 0; j < 4; ++j) {
        const unsigned hp = cvtpk(f[2*j], f[2*j+1]);
        const float h0 = __uint_as_float(hp << 16);
        const float h1 = __uint_as_float(hp & 0xffff0000u);
        h.u[j] = hp;
        lo.u[j] = cvtpk(f[2*j] - h0, f[2*j+1] - h1);
    }
}

// p *= dpp(p) with multiplicative identity fill (classic GCN scan step, VALU-only)
template<int CTRL, int RM>
__device__ __forceinline__ float dppmul(float p) {
    const int t = __builtin_amdgcn_update_dpp(
        __float_as_int(1.0f), __float_as_int(p), CTRL, RM, 0xf, false);
    return p * __int_as_float(t);
}

__global__ void __launch_bounds__(256, 7)
mem_net_kernel(const float* __restrict__ x,
               const float* __restrict__ q,
               const float* __restrict__ keys,
               const float* __restrict__ Wu,
               const float* __restrict__ bu,
               const int*   __restrict__ lens,
               const int*   __restrict__ labels,
               const int*   __restrict__ qlab,
               float*       __restrict__ out)
{
    __shared__ __align__(16) float zST[20][ZP];   // logits transposed: [col][row]
    __shared__ __align__(16) float combS[SS][4];  // {wTot0, wTot1, wTot2, rS} per s
    __shared__ __align__(16) float cS[TT];        // per-row scalar weight (row-indexed)
    __shared__ __align__(16) float red[4][DD];

    const int b   = blockIdx.x;
    const int tid = threadIdx.x;
    const int l   = tid & 63;
    const int w   = tid >> 6;
    const int n0  = l & 15;
    const int g   = l >> 4;
    const int kb  = g << 3;
    const int len = lens[b];
    const int ql  = qlab[b];

    // row reversal: thread tid owns row r = 255 - tid  => suffix(t) == prefix(tid)
    const int  r     = (TT - 1) - tid;
    const int  R0    = 192 - (w << 6);        // wave's lowest row
    const bool valid = (r < len);
    const bool wact  = (R0 < len);

    // ---- early independent loads ----
    const int labn = labels[(size_t)b * TT + r];
    float qv = 0.f;
    float rkv[SS];
    if (w == 0) {                  // wave 0 (rows 192-255) idle ~75% -> owns r_attn
        const int d = l & 31;
        qv = q[(size_t)b * DD + d];
        #pragma unroll
        for (int s = 0; s < SS; ++s) rkv[s] = keys[(size_t)(ql * SS + s) * DD + d];
    }

    // ---- K_all^T B-fragments hi/lo ----
    F8 kh0, kl0, kh1, kl1;
    {
        const float* kp = keys + (size_t)n0 * DD + kb;
        const float4 g0 = *reinterpret_cast<const float4*>(kp);
        const float4 g1 = *reinterpret_cast<const float4*>(kp + 4);
        split8(g0, g1, kh0, kl0);
        if (n0 < 4) {
            const float* kp1 = keys + (size_t)(16 + n0) * DD + kb;
            const float4 h0 = *reinterpret_cast<const float4*>(kp1);
            const float4 h1 = *reinterpret_cast<const float4*>(kp1 + 4);
            split8(h0, h1, kh1, kl1);
        } else {
            #pragma unroll
            for (int j = 0; j < 4; ++j) { kh1.u[j] = 0u; kl1.u[j] = 0u; }
        }
    }
    // ---- Wu B-fragments + bias ----
    F8 bw0, bw1;
    #pragma unroll
    for (int j = 0; j < 4; ++j) {
        const int k0 = kb + 2 * j;
        bw0.u[j] = cvtpk(Wu[k0 * DD + n0],      Wu[(k0 + 1) * DD + n0]);
        bw1.u[j] = cvtpk(Wu[k0 * DD + n0 + 16], Wu[(k0 + 1) * DD + n0 + 16]);
    }
    const float bub0 = bu[n0], bub1 = bu[n0 + 16];

    // ---- wave 0: r_attn = softmax_s(q . keys[ql][s]) -> combS[s][3] ----
    if (w == 0) {
        float pv[SS];
        #pragma unroll
        for (int s = 0; s < SS; ++s) pv[s] = qv * rkv[s];
        #pragma unroll
        for (int m = 16; m >= 1; m >>= 1) {
            #pragma unroll
            for (int s = 0; s < SS; ++s) pv[s] += __shfl_xor(pv[s], m);
        }
        float mm = pv[0];
        #pragma unroll
        for (int s = 1; s < SS; ++s) mm = fmaxf(mm, pv[s]);
        float e[SS], sum = 0.f;
        #pragma unroll
        for (int s = 0; s < SS; ++s) { e[s] = __expf(pv[s] - mm); sum += e[s]; }
        const float inv = frcp(sum);
        if (l == 0) {
            #pragma unroll
            for (int s = 0; s < SS; ++s) combS[s][3] = e[s] * inv;
        }
    }

    // ---- FRONT: QK^T via split-fp32 MFMA, transposed logit store ----
    F8 xh[4];
    if (wact) {
        #pragma unroll
        for (int rt = 0; rt < 4; ++rt) {
            const int rbase = R0 + (rt << 4);
            if (rbase < len) {                        // wave-uniform
                const float* xt = x + ((size_t)b * TT + rbase + n0) * DD + kb;
                const float4 f0 = *reinterpret_cast<const float4*>(xt);
                const float4 f1 = *reinterpret_cast<const float4*>(xt + 4);
                F8 xlo;
                split8(f0, f1, xh[rt], xlo);
                f32x4 z0 = {0.f, 0.f, 0.f, 0.f};
                f32x4 z1 = {0.f, 0.f, 0.f, 0.f};
                z0 = MFMA(xlo.v,    kh0.v, z0);
                z0 = MFMA(xh[rt].v, kl0.v, z0);
                z0 = MFMA(xh[rt].v, kh0.v, z0);
                z1 = MFMA(xlo.v,    kh1.v, z1);
                z1 = MFMA(xh[rt].v, kl1.v, z1);
                z1 = MFMA(xh[rt].v, kh1.v, z1);
                const int r0 = rbase + (g << 2);      // C layout: col=n0, rows g*4+reg
                *reinterpret_cast<f32x4*>(&zST[n0][r0]) = z0;
                if (n0 < 4)
                    *reinterpret_cast<f32x4*>(&zST[16 + n0][r0]) = z1;
            }
        }
    }
    // zST write->read is same-wave: DS pipe is in-order, no barrier needed.

    // ---- softmax over the 5 label-selected logits (fp32 exact) ----
    float a[SS];
    #pragma unroll
    for (int s = 0; s < SS; ++s) a[s] = 0.f;
    if (valid) {
        const int lab = (r < len - 1) ? labn : 0;
        float z[SS];
        #pragma unroll
        for (int s = 0; s < SS; ++s) z[s] = zST[5 * lab + s][r];
        float m = z[0];
        #pragma unroll
        for (int s = 1; s < SS; ++s) m = fmaxf(m, z[s]);
        float e[SS], sum = 0.f;
        #pragma unroll
        for (int s = 0; s < SS; ++s) { e[s] = __expf(z[s] - m); sum += e[s]; }
        const float inv = frcp(sum);
        #pragma unroll
        for (int s = 0; s < SS; ++s) a[s] = e[s] * inv;
    }

    // ---- exclusive prefix-product scan over tid (DPP, VALU-only) ----
    float excl[SS];
    if (wact) {
        #pragma unroll
        for (int s = 0; s < SS; ++s) {
            float ap = __shfl_up(a[s], 1);            // shift input: a'_l = a_{l-1}
            ap = (l == 0) ? 0.f : ap;
            float p = 1.f - ap;
            p = dppmul<0x111, 0xf>(p);                // row_shr:1
            p = dppmul<0x112, 0xf>(p);                // row_shr:2
            p = dppmul<0x114, 0xf>(p);                // row_shr:4
            p = dppmul<0x118, 0xf>(p);                // row_shr:8
            p = dppmul<0x142, 0xa>(p);                // row_bcast15 -> rows 1,3
            p = dppmul<0x143, 0xc>(p);                // row_bcast31 -> rows 2,3
            excl[s] = p;
            if (l == 63 && w < 3) combS[s][w] = p * (1.f - a[s]);  // wave total
        }
    } else {
        #pragma unroll
        for (int s = 0; s < SS; ++s) excl[s] = 1.f;
        if (l == 63 && w < 3) {
            #pragma unroll
            for (int s = 0; s < SS; ++s) combS[s][w] = 1.f;
        }
    }
    __syncthreads();                                  // publishes combS

    // ---- per-row scalar weight c -> cS[row] ----
    float c = 0.f;
    if (valid) {
        #pragma unroll
        for (int s = 0; s < SS; ++s) {
            const f32x4 v = *reinterpret_cast<const f32x4*>(&combS[s][0]);  // broadcast
            float term = v[3] * a[s] * excl[s];
            if (w > 0) term *= v[0];
            if (w > 1) term *= v[1];
            if (w > 2) term *= v[2];
            c += term;
        }
    }
    cS[r] = c;
    // cS write->read is same-wave rows: DS in-order suffices.

    // ---- BACK: MLP MFMA + sigmoid + c-weighted reduce ----
    float p0 = 0.f, p1 = 0.f;
    if (wact) {
        #pragma unroll
        for (int rt = 0; rt < 4; ++rt) {
            const int rbase = R0 + (rt << 4);
            if (rbase < len) {
                f32x4 acc0 = {0.f, 0.f, 0.f, 0.f};
                f32x4 acc1 = {0.f, 0.f, 0.f, 0.f};
                acc0 = MFMA(xh[rt].v, bw0.v, acc0);
                acc1 = MFMA(xh[rt].v, bw1.v, acc1);
                const float4 cf = *reinterpret_cast<const float4*>(&cS[rbase + (g << 2)]);
                const float cfa[4] = {cf.x, cf.y, cf.z, cf.w};
                #pragma unroll
                for (int rr = 0; rr < 4; ++rr) {
                    p0 += cfa[rr] * frcp(1.f + __expf(-(acc0[rr] + bub0)));
                    p1 += cfa[rr] * frcp(1.f + __expf(-(acc1[rr] + bub1)));
                }
            }
        }
    }
    p0 += __shfl_xor(p0, 16); p0 += __shfl_xor(p0, 32);
    p1 += __shfl_xor(p1, 16); p1 += __shfl_xor(p1, 32);
    if (l < 16) { red[w][l] = p0; red[w][l + 16] = p1; }
    __syncthreads();

    if (tid < DD) {
        out[(size_t)b * DD + tid] = red[0][tid] + red[1][tid] + red[2][tid] + red[3][tid];
    }
}

extern "C" void kernel_launch(void* const* d_in, const int* in_sizes, int n_in,
                              void* d_out, int out_size, void* d_ws, size_t ws_size,
                              hipStream_t stream) {
    const float* x      = (const float*)d_in[0];
    const float* q      = (const float*)d_in[1];
    const float* keys   = (const float*)d_in[2];
    const float* Wu     = (const float*)d_in[3];
    const float* bu     = (const float*)d_in[4];
    const int*   lens   = (const int*)d_in[5];
    const int*   labels = (const int*)d_in[6];
    const int*   qlab   = (const int*)d_in[7];
    float* out = (float*)d_out;

    hipLaunchKernelGGL(mem_net_kernel, dim3(4096), dim3(256), 0, stream,
                       x, q, keys, Wu, bu, lens, labels, qlab, out);
}